// Round 2
// baseline (378.410 us; speedup 1.0000x reference)
//
#include <hip/hip_runtime.h>
#include <hip/hip_fp16.h>
#include <math.h>

#define DDIM 256
#define NWAVES 4   // waves per block in prep
#define SEGW 4     // segments per block (one wave each) in segpool4
#define NEG_SENT -1.0e30f

// ---------- Kernel A (fallback only): offsets[i] = lower_bound(seg, i) ----------
__global__ void seg_offsets_kernel(const int* __restrict__ seg, int E, int S,
                                   int* __restrict__ offs) {
    int i = blockIdx.x * blockDim.x + threadIdx.x;
    if (i > S) return;
    int lo = 0, hi = E;
    while (lo < hi) {
        int mid = (lo + hi) >> 1;
        if (seg[mid] < i) lo = mid + 1; else hi = mid;
    }
    offs[i] = lo;
}

// ---------- Merged prep + offsets ----------
// Blocks [0, gridN): one wave per row — p = exp(z.w + b), f16 copy of z.
// Blocks [gridN, ...): binary-search segment offsets.
__global__ __launch_bounds__(256)
void prep_offs_kernel(const float4* __restrict__ z4,
                      const float* __restrict__ attn_w,
                      const float* __restrict__ attn_b,
                      uint2* __restrict__ z16,      // N x 64 uint2 (4 halves each)
                      float* __restrict__ pvec, int N, int gridN,
                      const int* __restrict__ seg, int E, int S,
                      int* __restrict__ offs) {
    if ((int)blockIdx.x >= gridN) {
        int i = ((int)blockIdx.x - gridN) * blockDim.x + threadIdx.x;
        if (i > S) return;
        int lo = 0, hi = E;
        while (lo < hi) {
            int mid = (lo + hi) >> 1;
            if (seg[mid] < i) lo = mid + 1; else hi = mid;
        }
        offs[i] = lo;
        return;
    }
    const int wave = threadIdx.x >> 6;
    const int lane = threadIdx.x & 63;
    const int row  = blockIdx.x * NWAVES + wave;
    if (row >= N) return;
    const float4 v = z4[(long)row * 64 + lane];
    __half2 h0 = __floats2half2_rn(v.x, v.y);
    __half2 h1 = __floats2half2_rn(v.z, v.w);
    uint2 h;
    h.x = *(unsigned int*)&h0;
    h.y = *(unsigned int*)&h1;
    z16[(long)row * 64 + lane] = h;
    const float4 wv = ((const float4*)attn_w)[lane];
    float part = v.x * wv.x + v.y * wv.y + v.z * wv.z + v.w * wv.w;
    #pragma unroll
    for (int sh = 32; sh >= 1; sh >>= 1) part += __shfl_xor(part, sh);
    if (lane == 0) pvec[row] = __expf(part + attn_b[0]);
}

// Fallback prep without the f16 copy.
__global__ __launch_bounds__(256)
void node_p_kernel(const float4* __restrict__ z4,
                   const float* __restrict__ attn_w,
                   const float* __restrict__ attn_b,
                   float* __restrict__ pvec, int N) {
    const int wave = threadIdx.x >> 6;
    const int lane = threadIdx.x & 63;
    const int row  = blockIdx.x * NWAVES + wave;
    if (row >= N) return;
    const float4 v  = z4[(long)row * 64 + lane];
    const float4 wv = ((const float4*)attn_w)[lane];
    float part = v.x * wv.x + v.y * wv.y + v.z * wv.z + v.w * wv.w;
    #pragma unroll
    for (int sh = 32; sh >= 1; sh >>= 1) part += __shfl_xor(part, sh);
    if (lane == 0) pvec[row] = __expf(part + attn_b[0]);
}

__device__ inline float4 h4_to_f4(uint2 h) {
    __half2 a = *(__half2*)&h.x;
    __half2 b = *(__half2*)&h.y;
    float2 fa = __half22float2(a);
    float2 fb = __half22float2(b);
    return make_float4(fa.x, fa.y, fb.x, fb.y);
}

// ---------- Kernel C: ONE WAVE PER SEGMENT, no LDS, no barriers ----------
// Lane l owns dims [4l, 4l+4). den is lane-uniform (every lane sums the same
// per-edge p), so no cross-lane reduction is needed at all.
__global__ __launch_bounds__(256)
void segpool4_kernel(const uint2* __restrict__ z16,
                     const float* __restrict__ pvec,
                     const int* __restrict__ idx,
                     const int* __restrict__ offs,
                     float* __restrict__ out, int S) {
    const int wave = threadIdx.x >> 6;
    const int lane = threadIdx.x & 63;
    const int s = blockIdx.x * SEGW + wave;
    if (s >= S) return;
    const int start = offs[s];
    const int end   = offs[s + 1];
    float4* __restrict__ out4 = (float4*)out;
    if (end <= start) {
        out4[(long)s * 64 + lane] = make_float4(0.f, 0.f, 0.f, 0.f);
        return;
    }

    float  den = 0.0f;
    float4 acc = make_float4(0.f, 0.f, 0.f, 0.f);

    int e = start;
    // Unroll-by-8: batch idx loads, then the dependent p/z loads (8-deep MLP).
    for (; e + 8 <= end; e += 8) {
        int rows[8];
        #pragma unroll
        for (int k = 0; k < 8; ++k) rows[k] = idx[e + k];
        float ps[8]; uint2 hs[8];
        #pragma unroll
        for (int k = 0; k < 8; ++k) {
            ps[k] = pvec[rows[k]];
            hs[k] = z16[((unsigned)rows[k] << 6) + lane];
        }
        #pragma unroll
        for (int k = 0; k < 8; ++k) {
            const float4 v = h4_to_f4(hs[k]);
            den   += ps[k];
            acc.x += ps[k] * v.x;
            acc.y += ps[k] * v.y;
            acc.z += ps[k] * v.z;
            acc.w += ps[k] * v.w;
        }
    }
    for (; e < end; ++e) {
        const int row  = idx[e];
        const float p  = pvec[row];
        const float4 v = h4_to_f4(z16[((unsigned)row << 6) + lane]);
        den   += p;
        acc.x += p * v.x;
        acc.y += p * v.y;
        acc.z += p * v.z;
        acc.w += p * v.w;
    }

    const float inv = 1.0f / den;
    out4[(long)s * 64 + lane] =
        make_float4(acc.x * inv, acc.y * inv, acc.z * inv, acc.w * inv);
}

// ---------- Fallback C': 4-wave-per-segment, f32 z (no copy) ----------
__global__ __launch_bounds__(256)
void segpool3_f32_kernel(const float4* __restrict__ z4,
                         const float* __restrict__ pvec,
                         const int* __restrict__ idx,
                         const int* __restrict__ offs,
                         float* __restrict__ out) {
    const int s     = blockIdx.x;
    const int start = offs[s];
    const int end   = offs[s + 1];
    const int tid   = threadIdx.x;
    if (end <= start) { out[(long)s * DDIM + tid] = 0.0f; return; }
    const int wave = tid >> 6;
    const int lane = tid & 63;
    float  den = 0.0f;
    float4 acc = make_float4(0.f, 0.f, 0.f, 0.f);
    int e = start + wave;
    for (; e + 7 * NWAVES < end; e += 8 * NWAVES) {
        int rows[8];
        #pragma unroll
        for (int k = 0; k < 8; ++k) rows[k] = idx[e + k * NWAVES];
        float ps[8]; float4 vs[8];
        #pragma unroll
        for (int k = 0; k < 8; ++k) {
            ps[k] = pvec[rows[k]];
            vs[k] = z4[(long)rows[k] * 64 + lane];
        }
        #pragma unroll
        for (int k = 0; k < 8; ++k) {
            den  += ps[k];
            acc.x += ps[k] * vs[k].x;
            acc.y += ps[k] * vs[k].y;
            acc.z += ps[k] * vs[k].z;
            acc.w += ps[k] * vs[k].w;
        }
    }
    for (; e < end; e += NWAVES) {
        const int row = idx[e];
        const float p = pvec[row];
        const float4 v = z4[(long)row * 64 + lane];
        den  += p;
        acc.x += p * v.x;
        acc.y += p * v.y;
        acc.z += p * v.z;
        acc.w += p * v.w;
    }
    __shared__ float lds_den[NWAVES];
    __shared__ float lds_acc[NWAVES][DDIM];
    if (lane == 0) lds_den[wave] = den;
    lds_acc[wave][4 * lane + 0] = acc.x;
    lds_acc[wave][4 * lane + 1] = acc.y;
    lds_acc[wave][4 * lane + 2] = acc.z;
    lds_acc[wave][4 * lane + 3] = acc.w;
    __syncthreads();
    const float D = lds_den[0] + lds_den[1] + lds_den[2] + lds_den[3];
    const float o = lds_acc[0][tid] + lds_acc[1][tid] +
                    lds_acc[2][tid] + lds_acc[3][tid];
    out[(long)s * DDIM + tid] = o / D;
}

// ---------- Last-resort fallback: fused online-softmax ----------
__global__ __launch_bounds__(256)
void segpool_fused_kernel(const float* __restrict__ z,
                          const float* __restrict__ attn_w,
                          const float* __restrict__ attn_b,
                          const int* __restrict__ idx,
                          const int* __restrict__ offs,
                          float* __restrict__ out) {
    const int s     = blockIdx.x;
    const int start = offs[s];
    const int end   = offs[s + 1];
    const int tid   = threadIdx.x;
    if (end <= start) { out[(long)s * DDIM + tid] = 0.0f; return; }
    const int wave = tid >> 6;
    const int lane = tid & 63;
    const float4 wv = ((const float4*)attn_w)[lane];
    const float  b  = attn_b[0];
    const float4* __restrict__ z4 = (const float4*)z;
    float  m = NEG_SENT, l = 0.0f;
    float4 acc = make_float4(0.f, 0.f, 0.f, 0.f);
    for (int e = start + wave; e < end; e += NWAVES) {
        const int   row = idx[e];
        const float4 v  = z4[(long)row * 64 + lane];
        float part = v.x * wv.x + v.y * wv.y + v.z * wv.z + v.w * wv.w;
        #pragma unroll
        for (int sh = 32; sh >= 1; sh >>= 1) part += __shfl_xor(part, sh);
        const float logit = part + b;
        const float nm    = fmaxf(m, logit);
        const float alpha = __expf(m - nm);
        const float p     = __expf(logit - nm);
        l = l * alpha + p;
        acc.x = acc.x * alpha + p * v.x;
        acc.y = acc.y * alpha + p * v.y;
        acc.z = acc.z * alpha + p * v.z;
        acc.w = acc.w * alpha + p * v.w;
        m = nm;
    }
    __shared__ float lds_m[NWAVES], lds_l[NWAVES];
    __shared__ float lds_acc[NWAVES][DDIM];
    if (lane == 0) { lds_m[wave] = m; lds_l[wave] = l; }
    __syncthreads();
    const float M = fmaxf(fmaxf(lds_m[0], lds_m[1]), fmaxf(lds_m[2], lds_m[3]));
    float den = 0.0f;
    #pragma unroll
    for (int w = 0; w < NWAVES; ++w) den += __expf(lds_m[w] - M) * lds_l[w];
    const float scale = __expf(m - M);
    lds_acc[wave][4 * lane + 0] = acc.x * scale;
    lds_acc[wave][4 * lane + 1] = acc.y * scale;
    lds_acc[wave][4 * lane + 2] = acc.z * scale;
    lds_acc[wave][4 * lane + 3] = acc.w * scale;
    __syncthreads();
    const float o = lds_acc[0][tid] + lds_acc[1][tid] +
                    lds_acc[2][tid] + lds_acc[3][tid];
    out[(long)s * DDIM + tid] = o / den;
}

extern "C" void kernel_launch(void* const* d_in, const int* in_sizes, int n_in,
                              void* d_out, int out_size, void* d_ws, size_t ws_size,
                              hipStream_t stream) {
    const float* z      = (const float*)d_in[0];
    const float* attn_w = (const float*)d_in[1];
    const float* attn_b = (const float*)d_in[2];
    const int*   idx    = (const int*)d_in[3];
    const int*   seg    = (const int*)d_in[4];
    float*       out    = (float*)d_out;

    const int E = in_sizes[3];
    const int S = out_size / DDIM;
    const int N = in_sizes[0] / DDIM;

    const int threads = 256;
    const int gridA = (S + 1 + threads - 1) / threads;
    const int gridN = (N + NWAVES - 1) / NWAVES;

    int* offs = (int*)d_ws;
    const size_t offs_bytes = (((size_t)(S + 1) * sizeof(int)) + 255) & ~(size_t)255;
    const size_t p_bytes    = (((size_t)N * sizeof(float)) + 255) & ~(size_t)255;
    const size_t z16_bytes  = (size_t)N * DDIM * sizeof(__half);
    const size_t need_full  = offs_bytes + p_bytes + z16_bytes;
    const size_t need_p     = offs_bytes + p_bytes;

    if (ws_size >= need_full) {
        float* pvec = (float*)((char*)d_ws + offs_bytes);
        uint2* z16  = (uint2*)((char*)d_ws + offs_bytes + p_bytes);
        // Merged prep + offsets: one launch, independent block ranges.
        prep_offs_kernel<<<gridN + gridA, threads, 0, stream>>>(
            (const float4*)z, attn_w, attn_b, z16, pvec, N, gridN,
            seg, E, S, offs);
        segpool4_kernel<<<(S + SEGW - 1) / SEGW, threads, 0, stream>>>(
            (const uint2*)z16, pvec, idx, offs, out, S);
    } else if (ws_size >= need_p) {
        float* pvec = (float*)((char*)d_ws + offs_bytes);
        seg_offsets_kernel<<<gridA, threads, 0, stream>>>(seg, E, S, offs);
        node_p_kernel<<<gridN, threads, 0, stream>>>(
            (const float4*)z, attn_w, attn_b, pvec, N);
        segpool3_f32_kernel<<<S, threads, 0, stream>>>(
            (const float4*)z, pvec, idx, offs, out);
    } else {
        seg_offsets_kernel<<<gridA, threads, 0, stream>>>(seg, E, S, offs);
        segpool_fused_kernel<<<S, threads, 0, stream>>>(
            z, attn_w, attn_b, idx, offs, out);
    }
}

// Round 3
// 373.119 us; speedup vs baseline: 1.0142x; 1.0142x over previous
//
#include <hip/hip_runtime.h>
#include <hip/hip_fp16.h>
#include <math.h>

#define DDIM 256
#define NWAVES 4   // waves per block in prep
#define SEGW 4     // segments per block (one wave each) in segpool
#define NEG_SENT -1.0e30f

// ---------- Kernel A (fallback only): offsets[i] = lower_bound(seg, i) ----------
__global__ void seg_offsets_kernel(const int* __restrict__ seg, int E, int S,
                                   int* __restrict__ offs) {
    int i = blockIdx.x * blockDim.x + threadIdx.x;
    if (i > S) return;
    int lo = 0, hi = E;
    while (lo < hi) {
        int mid = (lo + hi) >> 1;
        if (seg[mid] < i) lo = mid + 1; else hi = mid;
    }
    offs[i] = lo;
}

// ---------- Merged prep + offsets ----------
// Blocks [0, gridN): one wave per row — p = exp(z.w + b), f16 copy of z.
// Blocks [gridN, ...): binary-search segment offsets.
__global__ __launch_bounds__(256)
void prep_offs_kernel(const float4* __restrict__ z4,
                      const float* __restrict__ attn_w,
                      const float* __restrict__ attn_b,
                      uint2* __restrict__ z16,      // N x 64 uint2 (4 halves each)
                      float* __restrict__ pvec, int N, int gridN,
                      const int* __restrict__ seg, int E, int S,
                      int* __restrict__ offs) {
    if ((int)blockIdx.x >= gridN) {
        int i = ((int)blockIdx.x - gridN) * blockDim.x + threadIdx.x;
        if (i > S) return;
        int lo = 0, hi = E;
        while (lo < hi) {
            int mid = (lo + hi) >> 1;
            if (seg[mid] < i) lo = mid + 1; else hi = mid;
        }
        offs[i] = lo;
        return;
    }
    const int wave = threadIdx.x >> 6;
    const int lane = threadIdx.x & 63;
    const int row  = blockIdx.x * NWAVES + wave;
    if (row >= N) return;
    const float4 v = z4[(long)row * 64 + lane];
    __half2 h0 = __floats2half2_rn(v.x, v.y);
    __half2 h1 = __floats2half2_rn(v.z, v.w);
    uint2 h;
    h.x = *(unsigned int*)&h0;
    h.y = *(unsigned int*)&h1;
    z16[(long)row * 64 + lane] = h;
    const float4 wv = ((const float4*)attn_w)[lane];
    float part = v.x * wv.x + v.y * wv.y + v.z * wv.z + v.w * wv.w;
    #pragma unroll
    for (int sh = 32; sh >= 1; sh >>= 1) part += __shfl_xor(part, sh);
    if (lane == 0) pvec[row] = __expf(part + attn_b[0]);
}

// Fallback prep without the f16 copy.
__global__ __launch_bounds__(256)
void node_p_kernel(const float4* __restrict__ z4,
                   const float* __restrict__ attn_w,
                   const float* __restrict__ attn_b,
                   float* __restrict__ pvec, int N) {
    const int wave = threadIdx.x >> 6;
    const int lane = threadIdx.x & 63;
    const int row  = blockIdx.x * NWAVES + wave;
    if (row >= N) return;
    const float4 v  = z4[(long)row * 64 + lane];
    const float4 wv = ((const float4*)attn_w)[lane];
    float part = v.x * wv.x + v.y * wv.y + v.z * wv.z + v.w * wv.w;
    #pragma unroll
    for (int sh = 32; sh >= 1; sh >>= 1) part += __shfl_xor(part, sh);
    if (lane == 0) pvec[row] = __expf(part + attn_b[0]);
}

__device__ inline float4 h4_to_f4(unsigned int lo, unsigned int hi) {
    __half2 a = *(__half2*)&lo;
    __half2 b = *(__half2*)&hi;
    float2 fa = __half22float2(a);
    float2 fb = __half22float2(b);
    return make_float4(fa.x, fa.y, fb.x, fb.y);
}

// ---------- Kernel C: one wave/segment, split-wave dual-edge gather ----------
// Lanes 0-31 handle even-slot edges, lanes 32-63 odd-slot edges.
// Lane (half,hl) owns dims [8*hl, 8*hl+8) -> one 16B (dwordx4) load per edge,
// 1 KB per wave-instruction (two coalesced 512B segments). No LDS; halves
// combine with a single __shfl_xor(32) at the end.
__global__ __launch_bounds__(256)
void segpool5_kernel(const uint4* __restrict__ z16,  // N x 32 uint4 (512B rows)
                     const float* __restrict__ pvec,
                     const int* __restrict__ idx,
                     const int* __restrict__ offs,
                     float* __restrict__ out, int S) {
    const int wave = threadIdx.x >> 6;
    const int lane = threadIdx.x & 63;
    const int half = lane >> 5;   // 0 or 1
    const int hl   = lane & 31;   // lane within half
    const int s = blockIdx.x * SEGW + wave;
    if (s >= S) return;
    const int start = __builtin_amdgcn_readfirstlane(offs[s]);
    const int end   = __builtin_amdgcn_readfirstlane(offs[s + 1]);
    float4* __restrict__ out4 = (float4*)out;
    const long obase = (long)s * 64 + 2 * hl + half;
    if (end <= start) {
        out4[obase] = make_float4(0.f, 0.f, 0.f, 0.f);
        return;
    }

    float den = 0.f;
    float a0=0.f,a1=0.f,a2=0.f,a3=0.f,a4=0.f,a5=0.f,a6=0.f,a7=0.f;

    int e = start;
    // 8 edges per iteration = 4 pair-slots; this lane handles e + 2k + half.
    for (; e + 8 <= end; e += 8) {
        int rows[4];
        #pragma unroll
        for (int k = 0; k < 4; ++k) rows[k] = idx[e + 2 * k + half];
        float ps[4]; uint4 hs[4];
        #pragma unroll
        for (int k = 0; k < 4; ++k) {
            ps[k] = pvec[rows[k]];
            hs[k] = z16[((unsigned)rows[k] << 5) + hl];
        }
        #pragma unroll
        for (int k = 0; k < 4; ++k) {
            const float4 va = h4_to_f4(hs[k].x, hs[k].y);
            const float4 vb = h4_to_f4(hs[k].z, hs[k].w);
            den += ps[k];
            a0 += ps[k] * va.x; a1 += ps[k] * va.y;
            a2 += ps[k] * va.z; a3 += ps[k] * va.w;
            a4 += ps[k] * vb.x; a5 += ps[k] * vb.y;
            a6 += ps[k] * vb.z; a7 += ps[k] * vb.w;
        }
    }
    // pair tail
    for (; e + 2 <= end; e += 2) {
        const int   row = idx[e + half];
        const float p   = pvec[row];
        const uint4 h   = z16[((unsigned)row << 5) + hl];
        const float4 va = h4_to_f4(h.x, h.y);
        const float4 vb = h4_to_f4(h.z, h.w);
        den += p;
        a0 += p * va.x; a1 += p * va.y; a2 += p * va.z; a3 += p * va.w;
        a4 += p * vb.x; a5 += p * vb.y; a6 += p * vb.z; a7 += p * vb.w;
    }
    // single tail (only half 0 accumulates; shfl_xor combine fixes it up)
    if (e < end) {
        const int   row = idx[e];
        const float p   = pvec[row];
        const uint4 h   = z16[((unsigned)row << 5) + hl];
        if (half == 0) {
            const float4 va = h4_to_f4(h.x, h.y);
            const float4 vb = h4_to_f4(h.z, h.w);
            den += p;
            a0 += p * va.x; a1 += p * va.y; a2 += p * va.z; a3 += p * va.w;
            a4 += p * vb.x; a5 += p * vb.y; a6 += p * vb.z; a7 += p * vb.w;
        }
    }

    // combine the two halves (lane ^ 32 holds the other edge-parity partials
    // for the SAME dims)
    den += __shfl_xor(den, 32);
    a0 += __shfl_xor(a0, 32); a1 += __shfl_xor(a1, 32);
    a2 += __shfl_xor(a2, 32); a3 += __shfl_xor(a3, 32);
    a4 += __shfl_xor(a4, 32); a5 += __shfl_xor(a5, 32);
    a6 += __shfl_xor(a6, 32); a7 += __shfl_xor(a7, 32);

    const float inv = 1.0f / den;
    // half 0 writes dims [8hl, 8hl+4), half 1 writes [8hl+4, 8hl+8)
    const float4 o = (half == 0)
        ? make_float4(a0 * inv, a1 * inv, a2 * inv, a3 * inv)
        : make_float4(a4 * inv, a5 * inv, a6 * inv, a7 * inv);
    out4[obase] = o;
}

// ---------- Fallback C': 4-wave-per-segment, f32 z (no copy) ----------
__global__ __launch_bounds__(256)
void segpool3_f32_kernel(const float4* __restrict__ z4,
                         const float* __restrict__ pvec,
                         const int* __restrict__ idx,
                         const int* __restrict__ offs,
                         float* __restrict__ out) {
    const int s     = blockIdx.x;
    const int start = offs[s];
    const int end   = offs[s + 1];
    const int tid   = threadIdx.x;
    if (end <= start) { out[(long)s * DDIM + tid] = 0.0f; return; }
    const int wave = tid >> 6;
    const int lane = tid & 63;
    float  den = 0.0f;
    float4 acc = make_float4(0.f, 0.f, 0.f, 0.f);
    int e = start + wave;
    for (; e + 7 * NWAVES < end; e += 8 * NWAVES) {
        int rows[8];
        #pragma unroll
        for (int k = 0; k < 8; ++k) rows[k] = idx[e + k * NWAVES];
        float ps[8]; float4 vs[8];
        #pragma unroll
        for (int k = 0; k < 8; ++k) {
            ps[k] = pvec[rows[k]];
            vs[k] = z4[(long)rows[k] * 64 + lane];
        }
        #pragma unroll
        for (int k = 0; k < 8; ++k) {
            den  += ps[k];
            acc.x += ps[k] * vs[k].x;
            acc.y += ps[k] * vs[k].y;
            acc.z += ps[k] * vs[k].z;
            acc.w += ps[k] * vs[k].w;
        }
    }
    for (; e < end; e += NWAVES) {
        const int row = idx[e];
        const float p = pvec[row];
        const float4 v = z4[(long)row * 64 + lane];
        den  += p;
        acc.x += p * v.x;
        acc.y += p * v.y;
        acc.z += p * v.z;
        acc.w += p * v.w;
    }
    __shared__ float lds_den[NWAVES];
    __shared__ float lds_acc[NWAVES][DDIM];
    if (lane == 0) lds_den[wave] = den;
    lds_acc[wave][4 * lane + 0] = acc.x;
    lds_acc[wave][4 * lane + 1] = acc.y;
    lds_acc[wave][4 * lane + 2] = acc.z;
    lds_acc[wave][4 * lane + 3] = acc.w;
    __syncthreads();
    const float D = lds_den[0] + lds_den[1] + lds_den[2] + lds_den[3];
    const float o = lds_acc[0][tid] + lds_acc[1][tid] +
                    lds_acc[2][tid] + lds_acc[3][tid];
    out[(long)s * DDIM + tid] = o / D;
}

// ---------- Last-resort fallback: fused online-softmax ----------
__global__ __launch_bounds__(256)
void segpool_fused_kernel(const float* __restrict__ z,
                          const float* __restrict__ attn_w,
                          const float* __restrict__ attn_b,
                          const int* __restrict__ idx,
                          const int* __restrict__ offs,
                          float* __restrict__ out) {
    const int s     = blockIdx.x;
    const int start = offs[s];
    const int end   = offs[s + 1];
    const int tid   = threadIdx.x;
    if (end <= start) { out[(long)s * DDIM + tid] = 0.0f; return; }
    const int wave = tid >> 6;
    const int lane = tid & 63;
    const float4 wv = ((const float4*)attn_w)[lane];
    const float  b  = attn_b[0];
    const float4* __restrict__ z4 = (const float4*)z;
    float  m = NEG_SENT, l = 0.0f;
    float4 acc = make_float4(0.f, 0.f, 0.f, 0.f);
    for (int e = start + wave; e < end; e += NWAVES) {
        const int   row = idx[e];
        const float4 v  = z4[(long)row * 64 + lane];
        float part = v.x * wv.x + v.y * wv.y + v.z * wv.z + v.w * wv.w;
        #pragma unroll
        for (int sh = 32; sh >= 1; sh >>= 1) part += __shfl_xor(part, sh);
        const float logit = part + b;
        const float nm    = fmaxf(m, logit);
        const float alpha = __expf(m - nm);
        const float p     = __expf(logit - nm);
        l = l * alpha + p;
        acc.x = acc.x * alpha + p * v.x;
        acc.y = acc.y * alpha + p * v.y;
        acc.z = acc.z * alpha + p * v.z;
        acc.w = acc.w * alpha + p * v.w;
        m = nm;
    }
    __shared__ float lds_m[NWAVES], lds_l[NWAVES];
    __shared__ float lds_acc[NWAVES][DDIM];
    if (lane == 0) { lds_m[wave] = m; lds_l[wave] = l; }
    __syncthreads();
    const float M = fmaxf(fmaxf(lds_m[0], lds_m[1]), fmaxf(lds_m[2], lds_m[3]));
    float den = 0.0f;
    #pragma unroll
    for (int w = 0; w < NWAVES; ++w) den += __expf(lds_m[w] - M) * lds_l[w];
    const float scale = __expf(m - M);
    lds_acc[wave][4 * lane + 0] = acc.x * scale;
    lds_acc[wave][4 * lane + 1] = acc.y * scale;
    lds_acc[wave][4 * lane + 2] = acc.z * scale;
    lds_acc[wave][4 * lane + 3] = acc.w * scale;
    __syncthreads();
    const float o = lds_acc[0][tid] + lds_acc[1][tid] +
                    lds_acc[2][tid] + lds_acc[3][tid];
    out[(long)s * DDIM + tid] = o / den;
}

extern "C" void kernel_launch(void* const* d_in, const int* in_sizes, int n_in,
                              void* d_out, int out_size, void* d_ws, size_t ws_size,
                              hipStream_t stream) {
    const float* z      = (const float*)d_in[0];
    const float* attn_w = (const float*)d_in[1];
    const float* attn_b = (const float*)d_in[2];
    const int*   idx    = (const int*)d_in[3];
    const int*   seg    = (const int*)d_in[4];
    float*       out    = (float*)d_out;

    const int E = in_sizes[3];
    const int S = out_size / DDIM;
    const int N = in_sizes[0] / DDIM;

    const int threads = 256;
    const int gridA = (S + 1 + threads - 1) / threads;
    const int gridN = (N + NWAVES - 1) / NWAVES;

    int* offs = (int*)d_ws;
    const size_t offs_bytes = (((size_t)(S + 1) * sizeof(int)) + 255) & ~(size_t)255;
    const size_t p_bytes    = (((size_t)N * sizeof(float)) + 255) & ~(size_t)255;
    const size_t z16_bytes  = (size_t)N * DDIM * sizeof(__half);
    const size_t need_full  = offs_bytes + p_bytes + z16_bytes;
    const size_t need_p     = offs_bytes + p_bytes;

    if (ws_size >= need_full) {
        float* pvec = (float*)((char*)d_ws + offs_bytes);
        uint2* z16  = (uint2*)((char*)d_ws + offs_bytes + p_bytes);
        // Merged prep + offsets: one launch, independent block ranges.
        prep_offs_kernel<<<gridN + gridA, threads, 0, stream>>>(
            (const float4*)z, attn_w, attn_b, z16, pvec, N, gridN,
            seg, E, S, offs);
        segpool5_kernel<<<(S + SEGW - 1) / SEGW, threads, 0, stream>>>(
            (const uint4*)z16, pvec, idx, offs, out, S);
    } else if (ws_size >= need_p) {
        float* pvec = (float*)((char*)d_ws + offs_bytes);
        seg_offsets_kernel<<<gridA, threads, 0, stream>>>(seg, E, S, offs);
        node_p_kernel<<<gridN, threads, 0, stream>>>(
            (const float4*)z, attn_w, attn_b, pvec, N);
        segpool3_f32_kernel<<<S, threads, 0, stream>>>(
            (const float4*)z, pvec, idx, offs, out);
    } else {
        seg_offsets_kernel<<<gridA, threads, 0, stream>>>(seg, E, S, offs);
        segpool_fused_kernel<<<S, threads, 0, stream>>>(
            z, attn_w, attn_b, idx, offs, out);
    }
}